// Round 3
// baseline (3132.134 us; speedup 1.0000x reference)
//
#include <hip/hip_runtime.h>

typedef unsigned short u16;
typedef unsigned int u32;
typedef __bf16 bf16x8 __attribute__((ext_vector_type(8)));
typedef float f32x4 __attribute__((ext_vector_type(4)));
typedef u16 u16x8 __attribute__((ext_vector_type(8)));

#define IN_CH 256
#define HID 64
#define BSHIFT 8            // 256 nodes per bucket
#define BNODES 256
#define NBUK 391            // ceil(100000 / 256)
#define BCAP 10240          // avg 8192 edges/bucket, sigma~90 -> +22 sigma
#define TILE 8192           // edges per partition tile

__device__ __forceinline__ u16 f2bf(float f) {
  union { float f; unsigned u; } v; v.f = f;
  unsigned r = v.u + 0x7FFFu + ((v.u >> 16) & 1u);  // RNE
  return (u16)(r >> 16);
}
__device__ __forceinline__ float bf2f(u16 h) {
  union { unsigned u; float f; } v; v.u = ((unsigned)h) << 16;
  return v.f;
}

// transpose + bf16-convert weights: w1t[n][k] (64x256), w2t[n][k] (64x64)
__global__ void k_wprep(const float* __restrict__ W1, const float* __restrict__ W2,
                        u16* __restrict__ w1t, u16* __restrict__ w2t) {
  int t = blockIdx.x * blockDim.x + threadIdx.x;
  if (t < 64 * 256) {
    int n = t >> 8, k = t & 255;
    w1t[t] = f2bf(W1[k * 64 + n]);
  }
  int t2 = t - 64 * 256;
  if (t2 >= 0 && t2 < 64 * 64) {
    int n = t2 >> 6, k = t2 & 63;
    w2t[t2] = f2bf(W2[k * 64 + n]);
  }
}

// ---------------- phase A: LDS-staged bucket partition ----------------
// Edge packed as u32: src (bits 0-19) | dloc (bits 20-27).

__global__ __launch_bounds__(1024) void k_part(const int* __restrict__ e_src,
                                               const int* __restrict__ e_dst,
                                               int* __restrict__ bcnt,
                                               u32* __restrict__ bedge, int E) {
  __shared__ int lcnt[512];
  __shared__ int lscan[512];
  __shared__ int gbase[512];
  __shared__ int wsum[8];
  __shared__ u32 stag[TILE];
  __shared__ int dest[TILE];
  int t = threadIdx.x;
  int base = blockIdx.x * TILE;
  int here = E - base; if (here > TILE) here = TILE;

  if (t < 512) lcnt[t] = 0;
  __syncthreads();

  u32 m[8]; int bk[8]; int rk[8];
#pragma unroll
  for (int k = 0; k < 8; ++k) {
    int e = base + t + k * 1024;
    if (e < E) {
      int s = e_src[e], d = e_dst[e];
      bk[k] = d >> BSHIFT;
      m[k] = (u32)s | ((u32)(d & (BNODES - 1)) << 20);
      rk[k] = atomicAdd(&lcnt[bk[k]], 1);
    } else bk[k] = -1;
  }
  __syncthreads();

  // exclusive scan of lcnt[0..511] by threads 0..511 (8 waves)
  int lane = t & 63, w = t >> 6;
  int v = 0, x = 0;
  if (t < 512) { v = lcnt[t]; x = v; }
#pragma unroll
  for (int off = 1; off < 64; off <<= 1) {
    int y = __shfl_up(x, off);
    if (lane >= off) x += y;
  }
  if (t < 512 && lane == 63) wsum[w] = x;
  __syncthreads();
  if (t < 512) {
    int wo = 0;
    for (int i = 0; i < w; ++i) wo += wsum[i];
    lscan[t] = x - v + wo;
  }
  __syncthreads();

  // reserve global space per bucket
  if (t < NBUK) gbase[t] = t * BCAP + atomicAdd(&bcnt[t], lcnt[t]);
  __syncthreads();

  // place into LDS staging ordered by bucket
#pragma unroll
  for (int k = 0; k < 8; ++k) {
    if (bk[k] >= 0) {
      int p = lscan[bk[k]] + rk[k];
      stag[p] = m[k];
      dest[p] = gbase[bk[k]] + rk[k];
    }
  }
  __syncthreads();

  // coalesced copy-out (runs of same-bucket edges are contiguous)
#pragma unroll
  for (int k = 0; k < 8; ++k) {
    int p = t + k * 1024;
    if (p < here) bedge[dest[p]] = stag[p];
  }
}

// ---------------- phase B: per-bucket degree histogram -> dinv ----------------

__global__ __launch_bounds__(256) void k_deg(const int* __restrict__ bcnt,
                                             const u32* __restrict__ bedge,
                                             float* __restrict__ dinv, int N) {
  __shared__ int h[BNODES];
  int b = blockIdx.x, t = threadIdx.x;
  h[t] = 0;
  __syncthreads();
  int n = bcnt[b]; if (n > BCAP) n = BCAP;
  const u32* be = bedge + (size_t)b * BCAP;
  for (int i = t; i < n; i += 256) atomicAdd(&h[be[i] >> 20], 1);
  __syncthreads();
  int node = (b << BSHIFT) + t;
  if (node < N) dinv[node] = rsqrtf((float)(h[t] + 1));  // +1 self-loop
}

// ---------------- GEMMs (MFMA 16x16x32 bf16) ----------------
// A[m=lane&15][k=quad*8+j], B[n=lane&15][k=quad*8+j], D: col=lane&15, row=quad*4+reg.

__global__ __launch_bounds__(256) void k_gemm1(const float* __restrict__ x,
                                               const u16* __restrict__ w1t,
                                               u16* __restrict__ h1) {
  int lane = threadIdx.x & 63;
  int wave = threadIdx.x >> 6;
  int rowbase = blockIdx.x * 16;
  int colbase = wave * 16;
  int mn = lane & 15, quad = lane >> 4;
  f32x4 acc = {0.f, 0.f, 0.f, 0.f};
  const float* arow = x + (size_t)(rowbase + mn) * IN_CH + quad * 8;
  const u16* brow = w1t + (colbase + mn) * IN_CH + quad * 8;
#pragma unroll
  for (int kc = 0; kc < 8; ++kc) {
    float4 a0 = *(const float4*)(arow + kc * 32);
    float4 a1 = *(const float4*)(arow + kc * 32 + 4);
    u16x8 au;
    au[0] = f2bf(a0.x); au[1] = f2bf(a0.y); au[2] = f2bf(a0.z); au[3] = f2bf(a0.w);
    au[4] = f2bf(a1.x); au[5] = f2bf(a1.y); au[6] = f2bf(a1.z); au[7] = f2bf(a1.w);
    u16x8 bu = *(const u16x8*)(brow + kc * 32);
    acc = __builtin_amdgcn_mfma_f32_16x16x32_bf16(
        __builtin_bit_cast(bf16x8, au), __builtin_bit_cast(bf16x8, bu), acc, 0, 0, 0);
  }
#pragma unroll
  for (int r = 0; r < 4; ++r) {
    int row = rowbase + quad * 4 + r;
    h1[(size_t)row * HID + colbase + mn] = f2bf(acc[r]);
  }
}

__global__ __launch_bounds__(256) void k_gemm2(const u16* __restrict__ g1,
                                               const u16* __restrict__ w2t,
                                               u16* __restrict__ h2) {
  int lane = threadIdx.x & 63;
  int wave = threadIdx.x >> 6;
  int rowbase = blockIdx.x * 16;
  int colbase = wave * 16;
  int mn = lane & 15, quad = lane >> 4;
  f32x4 acc = {0.f, 0.f, 0.f, 0.f};
  const u16* arow = g1 + (size_t)(rowbase + mn) * HID + quad * 8;
  const u16* brow = w2t + (colbase + mn) * HID + quad * 8;
#pragma unroll
  for (int kc = 0; kc < 2; ++kc) {
    u16x8 au = *(const u16x8*)(arow + kc * 32);
    u16x8 bu = *(const u16x8*)(brow + kc * 32);
    acc = __builtin_amdgcn_mfma_f32_16x16x32_bf16(
        __builtin_bit_cast(bf16x8, au), __builtin_bit_cast(bf16x8, bu), acc, 0, 0, 0);
  }
#pragma unroll
  for (int r = 0; r < 4; ++r) {
    int row = rowbase + quad * 4 + r;
    h2[(size_t)row * HID + colbase + mn] = f2bf(acc[r]);
  }
}

// ---------------- aggregation: 1 block per bucket, LDS fp32 accumulator ----------------

template <bool RELU, bool BF16OUT>
__global__ __launch_bounds__(1024) void k_agg(const u16* __restrict__ hin,
                                              const int* __restrict__ bcnt,
                                              const u32* __restrict__ bedge,
                                              const float* __restrict__ dinv,
                                              const float* __restrict__ bias,
                                              void* __restrict__ outv, int N) {
  __shared__ float acc[BNODES * 64];  // 64 KB
  __shared__ float dloc[BNODES];
  int b = blockIdx.x, t = threadIdx.x;
  int lane = t & 63, w = t >> 6;
#pragma unroll
  for (int k = 0; k < 16; ++k) acc[t + k * 1024] = 0.f;
  if (t < BNODES) {
    int node = (b << BSHIFT) + t;
    dloc[t] = (node < N) ? dinv[node] : 0.f;
  }
  __syncthreads();

  int n = bcnt[b]; if (n > BCAP) n = BCAP;
  const u32* be = bedge + (size_t)b * BCAP;

  for (int i0 = w * 64; i0 < n; i0 += 16 * 64) {
    int i = i0 + lane;
    u32 m = 0; float nw = 0.f;
    if (i < n) {
      m = be[i];
      nw = dinv[m & 0xFFFFF] * dloc[m >> 20];
    }
    int cnt = n - i0; if (cnt > 64) cnt = 64;
    if (cnt == 64) {
#pragma unroll 8
      for (int j = 0; j < 64; ++j) {
        u32 mj = __shfl(m, j);
        float nj = __shfl(nw, j);
        int idx = (int)(mj & 0xFFFFF) * 64 + lane;
        float g = bf2f(hin[idx]);
        atomicAdd(&acc[((mj >> 20) << 6) + lane], nj * g);
      }
    } else {
      for (int j = 0; j < cnt; ++j) {
        u32 mj = __shfl(m, j);
        float nj = __shfl(nw, j);
        int idx = (int)(mj & 0xFFFFF) * 64 + lane;
        float g = bf2f(hin[idx]);
        atomicAdd(&acc[((mj >> 20) << 6) + lane], nj * g);
      }
    }
  }
  __syncthreads();

  // epilogue: self-loop + bias (+relu), coalesced store
#pragma unroll
  for (int k = 0; k < 16; ++k) {
    int idx = t + k * 1024;       // nodeLocal*64 + ch
    int nl = idx >> 6, ch = idx & 63;
    int node = (b << BSHIFT) + nl;
    if (node < N) {
      float di = dloc[nl];
      float vv = acc[idx] + di * di * bf2f(hin[node * 64 + ch]) + bias[ch];
      if (RELU) vv = fmaxf(vv, 0.f);
      if (BF16OUT) ((u16*)outv)[(size_t)node * 64 + ch] = f2bf(vv);
      else ((float*)outv)[(size_t)node * 64 + ch] = vv;
    }
  }
}

// ---------------- host ----------------

extern "C" void kernel_launch(void* const* d_in, const int* in_sizes, int n_in,
                              void* d_out, int out_size, void* d_ws, size_t ws_size,
                              hipStream_t stream) {
  const float* x = (const float*)d_in[0];
  const int* ei = (const int*)d_in[1];  // [2][E] int32
  const float* W1 = (const float*)d_in[2];
  const float* b1 = (const float*)d_in[3];
  const float* W2 = (const float*)d_in[4];
  const float* b2 = (const float*)d_in[5];
  float* out = (float*)d_out;

  const int N = in_sizes[0] / IN_CH;  // 100000
  const int E = in_sizes[1] / 2;      // 3200000
  const int* e_src = ei;
  const int* e_dst = ei + E;

  size_t off = 0;
  auto carve = [&](size_t bytes) -> char* {
    char* p = (char*)d_ws + off;
    off += (bytes + 255) & ~(size_t)255;
    return p;
  };
  int* bcnt = (int*)carve((size_t)NBUK * 4);
  u32* bedge = (u32*)carve((size_t)NBUK * BCAP * 4);  // 16 MB
  float* dinv = (float*)carve((size_t)N * 4);
  u16* w1t = (u16*)carve(64 * 256 * 2);
  u16* w2t = (u16*)carve(64 * 64 * 2);
  u16* h1 = (u16*)carve((size_t)N * HID * 2);
  u16* g1 = (u16*)carve((size_t)N * HID * 2);
  u16* h2 = (u16*)carve((size_t)N * HID * 2);

  const int n_tiles = (E + TILE - 1) / TILE;  // 391

  hipMemsetAsync(bcnt, 0, (size_t)NBUK * 4, stream);
  k_wprep<<<(64 * 256 + 64 * 64 + 255) / 256, 256, 0, stream>>>(W1, W2, w1t, w2t);
  k_part<<<n_tiles, 1024, 0, stream>>>(e_src, e_dst, bcnt, bedge, E);
  k_deg<<<NBUK, 256, 0, stream>>>(bcnt, bedge, dinv, N);
  k_gemm1<<<N / 16, 256, 0, stream>>>(x, w1t, h1);
  k_agg<true, true><<<NBUK, 1024, 0, stream>>>(h1, bcnt, bedge, dinv, b1, g1, N);
  k_gemm2<<<N / 16, 256, 0, stream>>>(g1, w2t, h2);
  k_agg<false, false><<<NBUK, 1024, 0, stream>>>(h2, bcnt, bedge, dinv, b2, out, N);
}

// Round 4
// 439.446 us; speedup vs baseline: 7.1275x; 7.1275x over previous
//
#include <hip/hip_runtime.h>

typedef unsigned short u16;
typedef unsigned int u32;
typedef __bf16 bf16x8 __attribute__((ext_vector_type(8)));
typedef float f32x4 __attribute__((ext_vector_type(4)));
typedef u16 u16x8 __attribute__((ext_vector_type(8)));

#define IN_CH 256
#define HID 64
#define BSHIFT 8            // 256 nodes per bucket
#define BNODES 256
#define NBUK 391            // ceil(100000 / 256)
#define BCAP 10240          // avg 8184 edges/bucket, sigma~90 -> +22 sigma headroom
#define TILE 8192           // edges per partition tile

__device__ __forceinline__ u16 f2bf(float f) {
  union { float f; unsigned u; } v; v.f = f;
  unsigned r = v.u + 0x7FFFu + ((v.u >> 16) & 1u);  // RNE
  return (u16)(r >> 16);
}
__device__ __forceinline__ float bf2f(u16 h) {
  union { unsigned u; float f; } v; v.u = ((unsigned)h) << 16;
  return v.f;
}

// transpose + bf16-convert weights: w1t[n][k] (64x256), w2t[n][k] (64x64)
__global__ void k_wprep(const float* __restrict__ W1, const float* __restrict__ W2,
                        u16* __restrict__ w1t, u16* __restrict__ w2t) {
  int t = blockIdx.x * blockDim.x + threadIdx.x;
  if (t < 64 * 256) {
    int n = t >> 8, k = t & 255;
    w1t[t] = f2bf(W1[k * 64 + n]);
  }
  int t2 = t - 64 * 256;
  if (t2 >= 0 && t2 < 64 * 64) {
    int n = t2 >> 6, k = t2 & 63;
    w2t[t2] = f2bf(W2[k * 64 + n]);
  }
}

// ---------------- phase A: LDS-staged bucket partition ----------------
// Edge packed as u32: src (bits 0-19) | dloc (bits 20-27). Int LDS atomics only.

__global__ __launch_bounds__(1024) void k_part(const int* __restrict__ e_src,
                                               const int* __restrict__ e_dst,
                                               int* __restrict__ bcnt,
                                               u32* __restrict__ bedge, int E) {
  __shared__ int lcnt[512];
  __shared__ int lscan[512];
  __shared__ int gbase[512];
  __shared__ int wsum[8];
  __shared__ u32 stag[TILE];
  __shared__ int dest[TILE];
  int t = threadIdx.x;
  int base = blockIdx.x * TILE;
  int here = E - base; if (here > TILE) here = TILE;

  if (t < 512) lcnt[t] = 0;
  __syncthreads();

  u32 m[8]; int bk[8]; int rk[8];
#pragma unroll
  for (int k = 0; k < 8; ++k) {
    int e = base + t + k * 1024;
    if (e < E) {
      int s = e_src[e], d = e_dst[e];
      bk[k] = d >> BSHIFT;
      m[k] = (u32)s | ((u32)(d & (BNODES - 1)) << 20);
      rk[k] = atomicAdd(&lcnt[bk[k]], 1);
    } else bk[k] = -1;
  }
  __syncthreads();

  // exclusive scan of lcnt[0..511] by threads 0..511 (8 waves)
  int lane = t & 63, w = t >> 6;
  int v = 0, x = 0;
  if (t < 512) { v = lcnt[t]; x = v; }
#pragma unroll
  for (int off = 1; off < 64; off <<= 1) {
    int y = __shfl_up(x, off);
    if (lane >= off) x += y;
  }
  if (t < 512 && lane == 63) wsum[w] = x;
  __syncthreads();
  if (t < 512) {
    int wo = 0;
    for (int i = 0; i < w; ++i) wo += wsum[i];
    lscan[t] = x - v + wo;
  }
  __syncthreads();

  // reserve global space per bucket
  if (t < NBUK) gbase[t] = t * BCAP + atomicAdd(&bcnt[t], lcnt[t]);
  __syncthreads();

  // place into LDS staging ordered by bucket
#pragma unroll
  for (int k = 0; k < 8; ++k) {
    if (bk[k] >= 0) {
      int p = lscan[bk[k]] + rk[k];
      stag[p] = m[k];
      dest[p] = gbase[bk[k]] + rk[k];
    }
  }
  __syncthreads();

  // coalesced copy-out (runs of same-bucket edges are contiguous)
#pragma unroll
  for (int k = 0; k < 8; ++k) {
    int p = t + k * 1024;
    if (p < here) bedge[dest[p]] = stag[p];
  }
}

// ---------------- phase B: per-bucket counting sort by dst (in-place) ----------------
// Also emits rptr/rcnt/dinv. Int LDS atomics only.

__global__ __launch_bounds__(1024) void k_sort(const int* __restrict__ bcnt,
                                               u32* __restrict__ bedge,
                                               int* __restrict__ rptr,
                                               int* __restrict__ rcnt,
                                               float* __restrict__ dinv, int N) {
  __shared__ u32 stag[BCAP];     // 40 KB
  __shared__ int hist[BNODES];
  __shared__ int cur[BNODES];
  __shared__ int wsum4[4];
  int b = blockIdx.x, t = threadIdx.x;
  if (t < BNODES) hist[t] = 0;
  __syncthreads();
  int n = bcnt[b]; if (n > BCAP) n = BCAP;
  u32* be = bedge + (size_t)b * BCAP;

  for (int i = t; i < n; i += 1024) atomicAdd(&hist[be[i] >> 20], 1);
  __syncthreads();

  // exclusive scan of hist[0..255] by threads 0..255 (4 waves)
  int lane = t & 63, w = t >> 6;
  int v = 0, x = 0;
  if (t < BNODES) { v = hist[t]; x = v; }
#pragma unroll
  for (int off = 1; off < 64; off <<= 1) {
    int y = __shfl_up(x, off);
    if (lane >= off) x += y;
  }
  if (t < BNODES && lane == 63) wsum4[w] = x;
  __syncthreads();
  if (t < BNODES) {
    int wo = 0;
    for (int i = 0; i < w; ++i) wo += wsum4[i];
    int ex = x - v + wo;
    cur[t] = ex;
    int node = (b << BSHIFT) + t;
    if (node < N) {
      rptr[node] = b * BCAP + ex;
      rcnt[node] = v;
      dinv[node] = rsqrtf((float)(v + 1));  // +1 self-loop
    }
  }
  __syncthreads();

  // rank + scatter into LDS (sorted by dloc)
  for (int i = t; i < n; i += 1024) {
    u32 m = be[i];
    int p = atomicAdd(&cur[m >> 20], 1);
    stag[p] = m;
  }
  __syncthreads();

  // in-place coalesced writeback
  for (int i = t; i < n; i += 1024) be[i] = stag[i];
}

// ---------------- phase C: per-edge norm = dinv[src]*dinv[dst] ----------------

__global__ __launch_bounds__(1024) void k_norm(const int* __restrict__ bcnt,
                                               const u32* __restrict__ bedge,
                                               const float* __restrict__ dinv,
                                               float* __restrict__ snorm, int N) {
  __shared__ float dl[BNODES];
  int b = blockIdx.x, t = threadIdx.x;
  if (t < BNODES) {
    int node = (b << BSHIFT) + t;
    dl[t] = (node < N) ? dinv[node] : 0.f;
  }
  __syncthreads();
  int n = bcnt[b]; if (n > BCAP) n = BCAP;
  const u32* be = bedge + (size_t)b * BCAP;
  float* sn = snorm + (size_t)b * BCAP;
  for (int i = t; i < n; i += 1024) {
    u32 m = be[i];
    sn[i] = dinv[m & 0xFFFFF] * dl[m >> 20];
  }
}

// ---------------- GEMMs (MFMA 16x16x32 bf16) ----------------
// A[m=lane&15][k=quad*8+j], B[n=lane&15][k=quad*8+j], D: col=lane&15, row=quad*4+reg.

__global__ __launch_bounds__(256) void k_gemm1(const float* __restrict__ x,
                                               const u16* __restrict__ w1t,
                                               u16* __restrict__ h1) {
  int lane = threadIdx.x & 63;
  int wave = threadIdx.x >> 6;
  int rowbase = blockIdx.x * 16;
  int colbase = wave * 16;
  int mn = lane & 15, quad = lane >> 4;
  f32x4 acc = {0.f, 0.f, 0.f, 0.f};
  const float* arow = x + (size_t)(rowbase + mn) * IN_CH + quad * 8;
  const u16* brow = w1t + (colbase + mn) * IN_CH + quad * 8;
#pragma unroll
  for (int kc = 0; kc < 8; ++kc) {
    float4 a0 = *(const float4*)(arow + kc * 32);
    float4 a1 = *(const float4*)(arow + kc * 32 + 4);
    u16x8 au;
    au[0] = f2bf(a0.x); au[1] = f2bf(a0.y); au[2] = f2bf(a0.z); au[3] = f2bf(a0.w);
    au[4] = f2bf(a1.x); au[5] = f2bf(a1.y); au[6] = f2bf(a1.z); au[7] = f2bf(a1.w);
    u16x8 bu = *(const u16x8*)(brow + kc * 32);
    acc = __builtin_amdgcn_mfma_f32_16x16x32_bf16(
        __builtin_bit_cast(bf16x8, au), __builtin_bit_cast(bf16x8, bu), acc, 0, 0, 0);
  }
#pragma unroll
  for (int r = 0; r < 4; ++r) {
    int row = rowbase + quad * 4 + r;
    h1[(size_t)row * HID + colbase + mn] = f2bf(acc[r]);
  }
}

__global__ __launch_bounds__(256) void k_gemm2(const u16* __restrict__ g1,
                                               const u16* __restrict__ w2t,
                                               u16* __restrict__ h2) {
  int lane = threadIdx.x & 63;
  int wave = threadIdx.x >> 6;
  int rowbase = blockIdx.x * 16;
  int colbase = wave * 16;
  int mn = lane & 15, quad = lane >> 4;
  f32x4 acc = {0.f, 0.f, 0.f, 0.f};
  const u16* arow = g1 + (size_t)(rowbase + mn) * HID + quad * 8;
  const u16* brow = w2t + (colbase + mn) * HID + quad * 8;
#pragma unroll
  for (int kc = 0; kc < 2; ++kc) {
    u16x8 au = *(const u16x8*)(arow + kc * 32);
    u16x8 bu = *(const u16x8*)(brow + kc * 32);
    acc = __builtin_amdgcn_mfma_f32_16x16x32_bf16(
        __builtin_bit_cast(bf16x8, au), __builtin_bit_cast(bf16x8, bu), acc, 0, 0, 0);
  }
#pragma unroll
  for (int r = 0; r < 4; ++r) {
    int row = rowbase + quad * 4 + r;
    h2[(size_t)row * HID + colbase + mn] = f2bf(acc[r]);
  }
}

// ---------------- aggregation: wave per node, scalar edge loads, no LDS/shfl ----------------

template <bool RELU, bool BF16OUT>
__global__ __launch_bounds__(256) void k_agg(const u16* __restrict__ hin,
                                             const int* __restrict__ rptr,
                                             const int* __restrict__ rcnt,
                                             const u32* __restrict__ sedge,
                                             const float* __restrict__ snorm,
                                             const float* __restrict__ bias,
                                             void* __restrict__ outv, int N) {
  int wid = blockIdx.x * 4 + (threadIdx.x >> 6);
  int lane = threadIdx.x & 63;
  if (wid >= N) return;
  int start = __builtin_amdgcn_readfirstlane(rptr[wid]);
  int len = __builtin_amdgcn_readfirstlane(rcnt[wid]);
  // self-loop: norm = 1/(deg+1) exactly
  float acc = (1.0f / (float)(len + 1)) * bf2f(hin[(size_t)wid * HID + lane]);
  int j = 0;
  for (; j + 4 <= len; j += 4) {
#pragma unroll
    for (int k = 0; k < 4; ++k) {
      int e = (int)(sedge[start + j + k] & 0xFFFFF);  // uniform -> s_load
      float nw = snorm[start + j + k];                // uniform -> s_load
      acc += nw * bf2f(hin[(size_t)e * HID + lane]);  // coalesced 128B gather
    }
  }
  for (; j < len; ++j) {
    int e = (int)(sedge[start + j] & 0xFFFFF);
    acc += snorm[start + j] * bf2f(hin[(size_t)e * HID + lane]);
  }
  acc += bias[lane];
  if (RELU) acc = fmaxf(acc, 0.f);
  if (BF16OUT) ((u16*)outv)[(size_t)wid * HID + lane] = f2bf(acc);
  else ((float*)outv)[(size_t)wid * HID + lane] = acc;
}

// ---------------- host ----------------

extern "C" void kernel_launch(void* const* d_in, const int* in_sizes, int n_in,
                              void* d_out, int out_size, void* d_ws, size_t ws_size,
                              hipStream_t stream) {
  const float* x = (const float*)d_in[0];
  const int* ei = (const int*)d_in[1];  // [2][E] int32
  const float* W1 = (const float*)d_in[2];
  const float* b1 = (const float*)d_in[3];
  const float* W2 = (const float*)d_in[4];
  const float* b2 = (const float*)d_in[5];
  float* out = (float*)d_out;

  const int N = in_sizes[0] / IN_CH;  // 100000
  const int E = in_sizes[1] / 2;      // 3200000
  const int* e_src = ei;
  const int* e_dst = ei + E;

  size_t off = 0;
  auto carve = [&](size_t bytes) -> char* {
    char* p = (char*)d_ws + off;
    off += (bytes + 255) & ~(size_t)255;
    return p;
  };
  int* bcnt = (int*)carve((size_t)NBUK * 4);
  u32* bedge = (u32*)carve((size_t)NBUK * BCAP * 4);    // 16 MB
  float* snorm = (float*)carve((size_t)NBUK * BCAP * 4); // 16 MB
  int* rptr = (int*)carve((size_t)N * 4);
  int* rcnt = (int*)carve((size_t)N * 4);
  float* dinv = (float*)carve((size_t)N * 4);
  u16* w1t = (u16*)carve(64 * 256 * 2);
  u16* w2t = (u16*)carve(64 * 64 * 2);
  u16* h1 = (u16*)carve((size_t)N * HID * 2);  // reused for h2
  u16* g1 = (u16*)carve((size_t)N * HID * 2);

  const int n_tiles = (E + TILE - 1) / TILE;  // 391

  hipMemsetAsync(bcnt, 0, (size_t)NBUK * 4, stream);
  k_wprep<<<(64 * 256 + 64 * 64 + 255) / 256, 256, 0, stream>>>(W1, W2, w1t, w2t);
  k_part<<<n_tiles, 1024, 0, stream>>>(e_src, e_dst, bcnt, bedge, E);
  k_sort<<<NBUK, 1024, 0, stream>>>(bcnt, bedge, rptr, rcnt, dinv, N);
  k_norm<<<NBUK, 1024, 0, stream>>>(bcnt, bedge, dinv, snorm, N);
  k_gemm1<<<N / 16, 256, 0, stream>>>(x, w1t, h1);
  k_agg<true, true><<<(N + 3) / 4, 256, 0, stream>>>(h1, rptr, rcnt, bedge, snorm, b1, g1, N);
  k_gemm2<<<N / 16, 256, 0, stream>>>(g1, w2t, h1);
  k_agg<false, false><<<(N + 3) / 4, 256, 0, stream>>>(h1, rptr, rcnt, bedge, snorm, b2, out, N);
}

// Round 5
// 398.991 us; speedup vs baseline: 7.8501x; 1.1014x over previous
//
#include <hip/hip_runtime.h>

typedef unsigned short u16;
typedef unsigned int u32;
typedef __bf16 bf16x8 __attribute__((ext_vector_type(8)));
typedef float f32x4 __attribute__((ext_vector_type(4)));
typedef u16 u16x8 __attribute__((ext_vector_type(8)));

#define IN_CH 256
#define HID 64
#define BSHIFT 8            // 256 nodes per bucket
#define BNODES 256
#define NBUK 391            // ceil(100000 / 256)
#define BCAP 10240          // avg 8184 edges/bucket; +22 sigma headroom
#define TILE 8192           // edges per partition tile

__device__ __forceinline__ u16 f2bf(float f) {
  union { float f; unsigned u; } v; v.f = f;
  unsigned r = v.u + 0x7FFFu + ((v.u >> 16) & 1u);  // RNE
  return (u16)(r >> 16);
}
__device__ __forceinline__ float bf2f(u16 h) {
  union { unsigned u; float f; } v; v.u = ((unsigned)h) << 16;
  return v.f;
}

// transpose + bf16-convert weights: w1t[n][k] (64x256), w2t[n][k] (64x64)
__global__ void k_wprep(const float* __restrict__ W1, const float* __restrict__ W2,
                        u16* __restrict__ w1t, u16* __restrict__ w2t) {
  int t = blockIdx.x * blockDim.x + threadIdx.x;
  if (t < 64 * 256) {
    int n = t >> 8, k = t & 255;
    w1t[t] = f2bf(W1[k * 64 + n]);
  }
  int t2 = t - 64 * 256;
  if (t2 >= 0 && t2 < 64 * 64) {
    int n = t2 >> 6, k = t2 & 63;
    w2t[t2] = f2bf(W2[k * 64 + n]);
  }
}

// ---------------- phase A: LDS-staged bucket partition ----------------
// Edge packed as u32: src (bits 0-19) | dloc (bits 20-27). Int LDS atomics only.

__global__ __launch_bounds__(1024) void k_part(const int* __restrict__ e_src,
                                               const int* __restrict__ e_dst,
                                               int* __restrict__ bcnt,
                                               u32* __restrict__ bedge, int E) {
  __shared__ int lcnt[512];
  __shared__ int lscan[512];
  __shared__ int gbase[512];
  __shared__ int wsum[8];
  __shared__ u32 stag[TILE];
  __shared__ int dest[TILE];
  int t = threadIdx.x;
  int base = blockIdx.x * TILE;
  int here = E - base; if (here > TILE) here = TILE;

  if (t < 512) lcnt[t] = 0;
  __syncthreads();

  u32 m[8]; int bk[8]; int rk[8];
#pragma unroll
  for (int k = 0; k < 8; ++k) {
    int e = base + t + k * 1024;
    if (e < E) {
      int s = e_src[e], d = e_dst[e];
      bk[k] = d >> BSHIFT;
      m[k] = (u32)s | ((u32)(d & (BNODES - 1)) << 20);
      rk[k] = atomicAdd(&lcnt[bk[k]], 1);
    } else bk[k] = -1;
  }
  __syncthreads();

  // exclusive scan of lcnt[0..511] by threads 0..511 (8 waves)
  int lane = t & 63, w = t >> 6;
  int v = 0, x = 0;
  if (t < 512) { v = lcnt[t]; x = v; }
#pragma unroll
  for (int off = 1; off < 64; off <<= 1) {
    int y = __shfl_up(x, off);
    if (lane >= off) x += y;
  }
  if (t < 512 && lane == 63) wsum[w] = x;
  __syncthreads();
  if (t < 512) {
    int wo = 0;
    for (int i = 0; i < w; ++i) wo += wsum[i];
    lscan[t] = x - v + wo;
  }
  __syncthreads();

  // reserve global space per bucket
  if (t < NBUK) gbase[t] = t * BCAP + atomicAdd(&bcnt[t], lcnt[t]);
  __syncthreads();

  // place into LDS staging ordered by bucket
#pragma unroll
  for (int k = 0; k < 8; ++k) {
    if (bk[k] >= 0) {
      int p = lscan[bk[k]] + rk[k];
      stag[p] = m[k];
      dest[p] = gbase[bk[k]] + rk[k];
    }
  }
  __syncthreads();

  // coalesced copy-out (runs of same-bucket edges are contiguous)
#pragma unroll
  for (int k = 0; k < 8; ++k) {
    int p = t + k * 1024;
    if (p < here) bedge[dest[p]] = stag[p];
  }
}

// ---------------- phase B: per-bucket counting sort by dst (in-place) ----------------
// Emits rptr/rcnt/dinv. Int LDS atomics only.

__global__ __launch_bounds__(1024) void k_sort(const int* __restrict__ bcnt,
                                               u32* __restrict__ bedge,
                                               int* __restrict__ rptr,
                                               int* __restrict__ rcnt,
                                               float* __restrict__ dinv, int N) {
  __shared__ u32 stag[BCAP];     // 40 KB
  __shared__ int hist[BNODES];
  __shared__ int cur[BNODES];
  __shared__ int wsum4[4];
  int b = blockIdx.x, t = threadIdx.x;
  if (t < BNODES) hist[t] = 0;
  __syncthreads();
  int n = bcnt[b]; if (n > BCAP) n = BCAP;
  u32* be = bedge + (size_t)b * BCAP;

  for (int i = t; i < n; i += 1024) atomicAdd(&hist[be[i] >> 20], 1);
  __syncthreads();

  // exclusive scan of hist[0..255] by threads 0..255 (4 waves)
  int lane = t & 63, w = t >> 6;
  int v = 0, x = 0;
  if (t < BNODES) { v = hist[t]; x = v; }
#pragma unroll
  for (int off = 1; off < 64; off <<= 1) {
    int y = __shfl_up(x, off);
    if (lane >= off) x += y;
  }
  if (t < BNODES && lane == 63) wsum4[w] = x;
  __syncthreads();
  if (t < BNODES) {
    int wo = 0;
    for (int i = 0; i < w; ++i) wo += wsum4[i];
    int ex = x - v + wo;
    cur[t] = ex;
    int node = (b << BSHIFT) + t;
    if (node < N) {
      rptr[node] = b * BCAP + ex;
      rcnt[node] = v;
      dinv[node] = rsqrtf((float)(v + 1));  // +1 self-loop
    }
  }
  __syncthreads();

  // rank + scatter into LDS (sorted by dloc)
  for (int i = t; i < n; i += 1024) {
    u32 m = be[i];
    int p = atomicAdd(&cur[m >> 20], 1);
    stag[p] = m;
  }
  __syncthreads();

  // in-place coalesced writeback
  for (int i = t; i < n; i += 1024) be[i] = stag[i];
}

// ---------------- GEMMs (MFMA 16x16x32 bf16), dinv-scaled epilogue ----------------
// A[m=lane&15][k=quad*8+j], B[n=lane&15][k=quad*8+j], D: col=lane&15, row=quad*4+reg.
// Output h'[row] = dinv[row] * (A@W)[row]  (GCN prescale trick: per-edge norm
// = dinv_src*dinv_dst factors as h'-sum times wave-uniform dinv_dst in agg).

__global__ __launch_bounds__(256) void k_gemm1(const float* __restrict__ x,
                                               const u16* __restrict__ w1t,
                                               const float* __restrict__ dinv,
                                               u16* __restrict__ h1) {
  int lane = threadIdx.x & 63;
  int wave = threadIdx.x >> 6;
  int rowbase = blockIdx.x * 16;
  int colbase = wave * 16;
  int mn = lane & 15, quad = lane >> 4;
  f32x4 acc = {0.f, 0.f, 0.f, 0.f};
  const float* arow = x + (size_t)(rowbase + mn) * IN_CH + quad * 8;
  const u16* brow = w1t + (colbase + mn) * IN_CH + quad * 8;
#pragma unroll
  for (int kc = 0; kc < 8; ++kc) {
    float4 a0 = *(const float4*)(arow + kc * 32);
    float4 a1 = *(const float4*)(arow + kc * 32 + 4);
    u16x8 au;
    au[0] = f2bf(a0.x); au[1] = f2bf(a0.y); au[2] = f2bf(a0.z); au[3] = f2bf(a0.w);
    au[4] = f2bf(a1.x); au[5] = f2bf(a1.y); au[6] = f2bf(a1.z); au[7] = f2bf(a1.w);
    u16x8 bu = *(const u16x8*)(brow + kc * 32);
    acc = __builtin_amdgcn_mfma_f32_16x16x32_bf16(
        __builtin_bit_cast(bf16x8, au), __builtin_bit_cast(bf16x8, bu), acc, 0, 0, 0);
  }
#pragma unroll
  for (int r = 0; r < 4; ++r) {
    int row = rowbase + quad * 4 + r;
    h1[(size_t)row * HID + colbase + mn] = f2bf(dinv[row] * acc[r]);
  }
}

__global__ __launch_bounds__(256) void k_gemm2(const u16* __restrict__ g1,
                                               const u16* __restrict__ w2t,
                                               const float* __restrict__ dinv,
                                               u16* __restrict__ h2) {
  int lane = threadIdx.x & 63;
  int wave = threadIdx.x >> 6;
  int rowbase = blockIdx.x * 16;
  int colbase = wave * 16;
  int mn = lane & 15, quad = lane >> 4;
  f32x4 acc = {0.f, 0.f, 0.f, 0.f};
  const u16* arow = g1 + (size_t)(rowbase + mn) * HID + quad * 8;
  const u16* brow = w2t + (colbase + mn) * HID + quad * 8;
#pragma unroll
  for (int kc = 0; kc < 2; ++kc) {
    u16x8 au = *(const u16x8*)(arow + kc * 32);
    u16x8 bu = *(const u16x8*)(brow + kc * 32);
    acc = __builtin_amdgcn_mfma_f32_16x16x32_bf16(
        __builtin_bit_cast(bf16x8, au), __builtin_bit_cast(bf16x8, bu), acc, 0, 0, 0);
  }
#pragma unroll
  for (int r = 0; r < 4; ++r) {
    int row = rowbase + quad * 4 + r;
    h2[(size_t)row * HID + colbase + mn] = f2bf(dinv[row] * acc[r]);
  }
}

// ---------------- aggregation: wave per node, scalar edges, no per-edge norm ----------------
// out[i] = dinv_i * (sum_e h'[src_e] + h'[i]) + bias

template <bool RELU, bool BF16OUT>
__global__ __launch_bounds__(256) void k_agg(const u16* __restrict__ hin,
                                             const int* __restrict__ rptr,
                                             const int* __restrict__ rcnt,
                                             const u32* __restrict__ sedge,
                                             const float* __restrict__ bias,
                                             void* __restrict__ outv, int N) {
  int wid = blockIdx.x * 4 + (threadIdx.x >> 6);
  int lane = threadIdx.x & 63;
  if (wid >= N) return;
  int start = __builtin_amdgcn_readfirstlane(rptr[wid]);
  int len = __builtin_amdgcn_readfirstlane(rcnt[wid]);
  float di = rsqrtf((float)(len + 1));
  // self-loop: dinv_i^2 * h[i] = dinv_i * h'[i]
  float acc = bf2f(hin[(size_t)wid * HID + lane]);
  const u32* se = sedge + start;
  int j = 0;
  for (; j + 8 <= len; j += 8) {
#pragma unroll
    for (int k = 0; k < 8; ++k) {
      int e = (int)(se[j + k] & 0xFFFFF);              // wave-uniform -> s_load
      acc += bf2f(hin[(size_t)e * HID + lane]);        // saddr + lane*2 gather
    }
  }
  for (; j < len; ++j) {
    int e = (int)(se[j] & 0xFFFFF);
    acc += bf2f(hin[(size_t)e * HID + lane]);
  }
  acc = di * acc + bias[lane];
  if (RELU) acc = fmaxf(acc, 0.f);
  if (BF16OUT) ((u16*)outv)[(size_t)wid * HID + lane] = f2bf(acc);
  else ((float*)outv)[(size_t)wid * HID + lane] = acc;
}

// ---------------- host ----------------

extern "C" void kernel_launch(void* const* d_in, const int* in_sizes, int n_in,
                              void* d_out, int out_size, void* d_ws, size_t ws_size,
                              hipStream_t stream) {
  const float* x = (const float*)d_in[0];
  const int* ei = (const int*)d_in[1];  // [2][E] int32
  const float* W1 = (const float*)d_in[2];
  const float* b1 = (const float*)d_in[3];
  const float* W2 = (const float*)d_in[4];
  const float* b2 = (const float*)d_in[5];
  float* out = (float*)d_out;

  const int N = in_sizes[0] / IN_CH;  // 100000
  const int E = in_sizes[1] / 2;      // 3200000
  const int* e_src = ei;
  const int* e_dst = ei + E;

  size_t off = 0;
  auto carve = [&](size_t bytes) -> char* {
    char* p = (char*)d_ws + off;
    off += (bytes + 255) & ~(size_t)255;
    return p;
  };
  int* bcnt = (int*)carve((size_t)NBUK * 4);
  u32* bedge = (u32*)carve((size_t)NBUK * BCAP * 4);  // 16 MB
  int* rptr = (int*)carve((size_t)N * 4);
  int* rcnt = (int*)carve((size_t)N * 4);
  float* dinv = (float*)carve((size_t)N * 4);
  u16* w1t = (u16*)carve(64 * 256 * 2);
  u16* w2t = (u16*)carve(64 * 64 * 2);
  u16* h1 = (u16*)carve((size_t)N * HID * 2);  // reused for h2
  u16* g1 = (u16*)carve((size_t)N * HID * 2);

  const int n_tiles = (E + TILE - 1) / TILE;  // 391

  hipMemsetAsync(bcnt, 0, (size_t)NBUK * 4, stream);
  k_wprep<<<(64 * 256 + 64 * 64 + 255) / 256, 256, 0, stream>>>(W1, W2, w1t, w2t);
  k_part<<<n_tiles, 1024, 0, stream>>>(e_src, e_dst, bcnt, bedge, E);
  k_sort<<<NBUK, 1024, 0, stream>>>(bcnt, bedge, rptr, rcnt, dinv, N);
  k_gemm1<<<N / 16, 256, 0, stream>>>(x, w1t, dinv, h1);
  k_agg<true, true><<<(N + 3) / 4, 256, 0, stream>>>(h1, rptr, rcnt, bedge, b1, g1, N);
  k_gemm2<<<N / 16, 256, 0, stream>>>(g1, w2t, dinv, h1);
  k_agg<false, false><<<(N + 3) / 4, 256, 0, stream>>>(h1, rptr, rcnt, bedge, b2, out, N);
}

// Round 6
// 371.684 us; speedup vs baseline: 8.4269x; 1.0735x over previous
//
#include <hip/hip_runtime.h>

typedef unsigned short u16;
typedef unsigned int u32;
typedef __bf16 bf16x8 __attribute__((ext_vector_type(8)));
typedef float f32x4 __attribute__((ext_vector_type(4)));
typedef u16 u16x8 __attribute__((ext_vector_type(8)));

#define IN_CH 256
#define HID 64
#define BSHIFT 8            // 256 nodes per bucket
#define BNODES 256
#define NBUK 391            // ceil(100000 / 256)
#define BCAP 10240          // avg 8184 edges/bucket; +22 sigma headroom
#define TILE 8192           // edges per partition tile

__device__ __forceinline__ u16 f2bf(float f) {
  union { float f; unsigned u; } v; v.f = f;
  unsigned r = v.u + 0x7FFFu + ((v.u >> 16) & 1u);  // RNE
  return (u16)(r >> 16);
}
__device__ __forceinline__ float bf2f(u16 h) {
  union { unsigned u; float f; } v; v.u = ((unsigned)h) << 16;
  return v.f;
}

// transpose + bf16-convert weights: w1t[n][k] (64x256), w2t[n][k] (64x64)
__global__ void k_wprep(const float* __restrict__ W1, const float* __restrict__ W2,
                        u16* __restrict__ w1t, u16* __restrict__ w2t) {
  int t = blockIdx.x * blockDim.x + threadIdx.x;
  if (t < 64 * 256) {
    int n = t >> 8, k = t & 255;
    w1t[t] = f2bf(W1[k * 64 + n]);
  }
  int t2 = t - 64 * 256;
  if (t2 >= 0 && t2 < 64 * 64) {
    int n = t2 >> 6, k = t2 & 63;
    w2t[t2] = f2bf(W2[k * 64 + n]);
  }
}

// ---------------- phase A: LDS-staged bucket partition ----------------
// Edge packed as u32: src (bits 0-19) | dloc (bits 20-27). Int LDS atomics only.

__global__ __launch_bounds__(1024) void k_part(const int* __restrict__ e_src,
                                               const int* __restrict__ e_dst,
                                               int* __restrict__ bcnt,
                                               u32* __restrict__ bedge, int E) {
  __shared__ int lcnt[512];
  __shared__ int lscan[512];
  __shared__ int gbase[512];
  __shared__ int wsum[8];
  __shared__ u32 stag[TILE];
  __shared__ int dest[TILE];
  int t = threadIdx.x;
  int base = blockIdx.x * TILE;
  int here = E - base; if (here > TILE) here = TILE;

  if (t < 512) lcnt[t] = 0;
  __syncthreads();

  u32 m[8]; int bk[8]; int rk[8];
#pragma unroll
  for (int k = 0; k < 8; ++k) {
    int e = base + t + k * 1024;
    if (e < E) {
      int s = e_src[e], d = e_dst[e];
      bk[k] = d >> BSHIFT;
      m[k] = (u32)s | ((u32)(d & (BNODES - 1)) << 20);
      rk[k] = atomicAdd(&lcnt[bk[k]], 1);
    } else bk[k] = -1;
  }
  __syncthreads();

  // exclusive scan of lcnt[0..511] by threads 0..511 (8 waves)
  int lane = t & 63, w = t >> 6;
  int v = 0, x = 0;
  if (t < 512) { v = lcnt[t]; x = v; }
#pragma unroll
  for (int off = 1; off < 64; off <<= 1) {
    int y = __shfl_up(x, off);
    if (lane >= off) x += y;
  }
  if (t < 512 && lane == 63) wsum[w] = x;
  __syncthreads();
  if (t < 512) {
    int wo = 0;
    for (int i = 0; i < w; ++i) wo += wsum[i];
    lscan[t] = x - v + wo;
  }
  __syncthreads();

  // reserve global space per bucket
  if (t < NBUK) gbase[t] = t * BCAP + atomicAdd(&bcnt[t], lcnt[t]);
  __syncthreads();

  // place into LDS staging ordered by bucket
#pragma unroll
  for (int k = 0; k < 8; ++k) {
    if (bk[k] >= 0) {
      int p = lscan[bk[k]] + rk[k];
      stag[p] = m[k];
      dest[p] = gbase[bk[k]] + rk[k];
    }
  }
  __syncthreads();

  // coalesced copy-out (runs of same-bucket edges are contiguous)
#pragma unroll
  for (int k = 0; k < 8; ++k) {
    int p = t + k * 1024;
    if (p < here) bedge[dest[p]] = stag[p];
  }
}

// ---------------- phase B: per-bucket counting sort by dst (in-place) ----------------
// Emits rptr/rcnt/dinv. Int LDS atomics only.

__global__ __launch_bounds__(1024) void k_sort(const int* __restrict__ bcnt,
                                               u32* __restrict__ bedge,
                                               int* __restrict__ rptr,
                                               int* __restrict__ rcnt,
                                               float* __restrict__ dinv, int N) {
  __shared__ u32 stag[BCAP];     // 40 KB
  __shared__ int hist[BNODES];
  __shared__ int cur[BNODES];
  __shared__ int wsum4[4];
  int b = blockIdx.x, t = threadIdx.x;
  if (t < BNODES) hist[t] = 0;
  __syncthreads();
  int n = bcnt[b]; if (n > BCAP) n = BCAP;
  u32* be = bedge + (size_t)b * BCAP;

  for (int i = t; i < n; i += 1024) atomicAdd(&hist[be[i] >> 20], 1);
  __syncthreads();

  // exclusive scan of hist[0..255] by threads 0..255 (4 waves)
  int lane = t & 63, w = t >> 6;
  int v = 0, x = 0;
  if (t < BNODES) { v = hist[t]; x = v; }
#pragma unroll
  for (int off = 1; off < 64; off <<= 1) {
    int y = __shfl_up(x, off);
    if (lane >= off) x += y;
  }
  if (t < BNODES && lane == 63) wsum4[w] = x;
  __syncthreads();
  if (t < BNODES) {
    int wo = 0;
    for (int i = 0; i < w; ++i) wo += wsum4[i];
    int ex = x - v + wo;
    cur[t] = ex;
    int node = (b << BSHIFT) + t;
    if (node < N) {
      rptr[node] = b * BCAP + ex;
      rcnt[node] = v;
      dinv[node] = rsqrtf((float)(v + 1));  // +1 self-loop
    }
  }
  __syncthreads();

  // rank + scatter into LDS (sorted by dloc)
  for (int i = t; i < n; i += 1024) {
    u32 m = be[i];
    int p = atomicAdd(&cur[m >> 20], 1);
    stag[p] = m;
  }
  __syncthreads();

  // in-place coalesced writeback
  for (int i = t; i < n; i += 1024) be[i] = stag[i];
}

// ---------------- GEMMs (MFMA 16x16x32 bf16), dinv-scaled epilogue ----------------
// A[m=lane&15][k=quad*8+j], B[n=lane&15][k=quad*8+j], D: col=lane&15, row=quad*4+reg.
// Output h'[row] = dinv[row] * (A@W)[row].
// ILP: ALL global loads hoisted into registers before convert/MFMA (VGPR ~110;
// round-5's VGPR=16 build serialized 8 dependent L2 round-trips -> 84us).

__global__ __launch_bounds__(256) void k_gemm1(const float* __restrict__ x,
                                               const u16* __restrict__ w1t,
                                               const float* __restrict__ dinv,
                                               u16* __restrict__ h1) {
  int lane = threadIdx.x & 63;
  int wave = threadIdx.x >> 6;
  int rowbase = blockIdx.x * 16;
  int colbase = wave * 16;
  int mn = lane & 15, quad = lane >> 4;
  const float* arow = x + (size_t)(rowbase + mn) * IN_CH + quad * 8;
  const u16* brow = w1t + (colbase + mn) * IN_CH + quad * 8;

  float4 a[16];
#pragma unroll
  for (int kc = 0; kc < 8; ++kc) {
    a[2 * kc] = *(const float4*)(arow + kc * 32);
    a[2 * kc + 1] = *(const float4*)(arow + kc * 32 + 4);
  }
  u16x8 bfr[8];
#pragma unroll
  for (int kc = 0; kc < 8; ++kc) bfr[kc] = *(const u16x8*)(brow + kc * 32);

  f32x4 acc = {0.f, 0.f, 0.f, 0.f};
#pragma unroll
  for (int kc = 0; kc < 8; ++kc) {
    float4 a0 = a[2 * kc], a1 = a[2 * kc + 1];
    u16x8 au;
    au[0] = f2bf(a0.x); au[1] = f2bf(a0.y); au[2] = f2bf(a0.z); au[3] = f2bf(a0.w);
    au[4] = f2bf(a1.x); au[5] = f2bf(a1.y); au[6] = f2bf(a1.z); au[7] = f2bf(a1.w);
    acc = __builtin_amdgcn_mfma_f32_16x16x32_bf16(
        __builtin_bit_cast(bf16x8, au), __builtin_bit_cast(bf16x8, bfr[kc]), acc, 0, 0, 0);
  }
#pragma unroll
  for (int r = 0; r < 4; ++r) {
    int row = rowbase + quad * 4 + r;
    h1[(size_t)row * HID + colbase + mn] = f2bf(dinv[row] * acc[r]);
  }
}

__global__ __launch_bounds__(256) void k_gemm2(const u16* __restrict__ g1,
                                               const u16* __restrict__ w2t,
                                               const float* __restrict__ dinv,
                                               u16* __restrict__ h2) {
  int lane = threadIdx.x & 63;
  int wave = threadIdx.x >> 6;
  int rowbase = blockIdx.x * 16;
  int colbase = wave * 16;
  int mn = lane & 15, quad = lane >> 4;
  const u16* arow = g1 + (size_t)(rowbase + mn) * HID + quad * 8;
  const u16* brow = w2t + (colbase + mn) * HID + quad * 8;
  u16x8 au0 = *(const u16x8*)(arow);
  u16x8 au1 = *(const u16x8*)(arow + 32);
  u16x8 bu0 = *(const u16x8*)(brow);
  u16x8 bu1 = *(const u16x8*)(brow + 32);
  f32x4 acc = {0.f, 0.f, 0.f, 0.f};
  acc = __builtin_amdgcn_mfma_f32_16x16x32_bf16(
      __builtin_bit_cast(bf16x8, au0), __builtin_bit_cast(bf16x8, bu0), acc, 0, 0, 0);
  acc = __builtin_amdgcn_mfma_f32_16x16x32_bf16(
      __builtin_bit_cast(bf16x8, au1), __builtin_bit_cast(bf16x8, bu1), acc, 0, 0, 0);
#pragma unroll
  for (int r = 0; r < 4; ++r) {
    int row = rowbase + quad * 4 + r;
    h2[(size_t)row * HID + colbase + mn] = f2bf(dinv[row] * acc[r]);
  }
}

// ---------------- aggregation: wave per node, scalar edges, multi-accumulator ----------------
// out[i] = dinv_i * (sum_e h'[src_e] + h'[i]) + bias

template <bool RELU, bool BF16OUT>
__global__ __launch_bounds__(256) void k_agg(const u16* __restrict__ hin,
                                             const int* __restrict__ rptr,
                                             const int* __restrict__ rcnt,
                                             const u32* __restrict__ sedge,
                                             const float* __restrict__ bias,
                                             void* __restrict__ outv, int N) {
  int wid = blockIdx.x * 4 + (threadIdx.x >> 6);
  int lane = threadIdx.x & 63;
  if (wid >= N) return;
  int start = __builtin_amdgcn_readfirstlane(rptr[wid]);
  int len = __builtin_amdgcn_readfirstlane(rcnt[wid]);
  float di = rsqrtf((float)(len + 1));
  float a0 = bf2f(hin[(size_t)wid * HID + lane]);  // self-loop: dinv*h'[i]
  float a1 = 0.f, a2 = 0.f, a3 = 0.f;
  const u32* se = sedge + start;
  int j = 0;
  for (; j + 16 <= len; j += 16) {
    u16 v[16];
#pragma unroll
    for (int k = 0; k < 16; ++k) {
      int e = (int)(se[j + k] & 0xFFFFF);  // wave-uniform -> s_load batch
      v[k] = hin[(size_t)e * HID + lane];  // 16 gathers in flight
    }
#pragma unroll
    for (int k = 0; k < 16; ++k) {
      float f = bf2f(v[k]);
      if ((k & 3) == 0) a0 += f;
      else if ((k & 3) == 1) a1 += f;
      else if ((k & 3) == 2) a2 += f;
      else a3 += f;
    }
  }
  if (j + 8 <= len) {
    u16 v[8];
#pragma unroll
    for (int k = 0; k < 8; ++k) {
      int e = (int)(se[j + k] & 0xFFFFF);
      v[k] = hin[(size_t)e * HID + lane];
    }
#pragma unroll
    for (int k = 0; k < 8; ++k) {
      float f = bf2f(v[k]);
      if ((k & 3) == 0) a0 += f;
      else if ((k & 3) == 1) a1 += f;
      else if ((k & 3) == 2) a2 += f;
      else a3 += f;
    }
    j += 8;
  }
  if (j + 4 <= len) {
    u16 v[4];
#pragma unroll
    for (int k = 0; k < 4; ++k) {
      int e = (int)(se[j + k] & 0xFFFFF);
      v[k] = hin[(size_t)e * HID + lane];
    }
    a0 += bf2f(v[0]); a1 += bf2f(v[1]); a2 += bf2f(v[2]); a3 += bf2f(v[3]);
    j += 4;
  }
  for (; j < len; ++j) {
    int e = (int)(se[j] & 0xFFFFF);
    a0 += bf2f(hin[(size_t)e * HID + lane]);
  }
  float acc = (a0 + a1) + (a2 + a3);
  acc = di * acc + bias[lane];
  if (RELU) acc = fmaxf(acc, 0.f);
  if (BF16OUT) ((u16*)outv)[(size_t)wid * HID + lane] = f2bf(acc);
  else ((float*)outv)[(size_t)wid * HID + lane] = acc;
}

// ---------------- host ----------------

extern "C" void kernel_launch(void* const* d_in, const int* in_sizes, int n_in,
                              void* d_out, int out_size, void* d_ws, size_t ws_size,
                              hipStream_t stream) {
  const float* x = (const float*)d_in[0];
  const int* ei = (const int*)d_in[1];  // [2][E] int32
  const float* W1 = (const float*)d_in[2];
  const float* b1 = (const float*)d_in[3];
  const float* W2 = (const float*)d_in[4];
  const float* b2 = (const float*)d_in[5];
  float* out = (float*)d_out;

  const int N = in_sizes[0] / IN_CH;  // 100000
  const int E = in_sizes[1] / 2;      // 3200000
  const int* e_src = ei;
  const int* e_dst = ei + E;

  size_t off = 0;
  auto carve = [&](size_t bytes) -> char* {
    char* p = (char*)d_ws + off;
    off += (bytes + 255) & ~(size_t)255;
    return p;
  };
  int* bcnt = (int*)carve((size_t)NBUK * 4);
  u32* bedge = (u32*)carve((size_t)NBUK * BCAP * 4);  // 16 MB
  int* rptr = (int*)carve((size_t)N * 4);
  int* rcnt = (int*)carve((size_t)N * 4);
  float* dinv = (float*)carve((size_t)N * 4);
  u16* w1t = (u16*)carve(64 * 256 * 2);
  u16* w2t = (u16*)carve(64 * 64 * 2);
  u16* h1 = (u16*)carve((size_t)N * HID * 2);  // reused for h2
  u16* g1 = (u16*)carve((size_t)N * HID * 2);

  const int n_tiles = (E + TILE - 1) / TILE;  // 391

  hipMemsetAsync(bcnt, 0, (size_t)NBUK * 4, stream);
  k_wprep<<<(64 * 256 + 64 * 64 + 255) / 256, 256, 0, stream>>>(W1, W2, w1t, w2t);
  k_part<<<n_tiles, 1024, 0, stream>>>(e_src, e_dst, bcnt, bedge, E);
  k_sort<<<NBUK, 1024, 0, stream>>>(bcnt, bedge, rptr, rcnt, dinv, N);
  k_gemm1<<<N / 16, 256, 0, stream>>>(x, w1t, dinv, h1);
  k_agg<true, true><<<(N + 3) / 4, 256, 0, stream>>>(h1, rptr, rcnt, bedge, b1, g1, N);
  k_gemm2<<<N / 16, 256, 0, stream>>>(g1, w2t, dinv, h1);
  k_agg<false, false><<<(N + 3) / 4, 256, 0, stream>>>(h1, rptr, rcnt, bedge, b2, out, N);
}

// Round 7
// 347.231 us; speedup vs baseline: 9.0203x; 1.0704x over previous
//
#include <hip/hip_runtime.h>

typedef unsigned short u16;
typedef unsigned int u32;
typedef __bf16 bf16x8 __attribute__((ext_vector_type(8)));
typedef float f32x4 __attribute__((ext_vector_type(4)));
typedef u16 u16x8 __attribute__((ext_vector_type(8)));

#define IN_CH 256
#define HID 64
#define BSHIFT 8            // 256 nodes per bucket
#define BNODES 256
#define NBUK 391            // ceil(100000 / 256)
#define BCAP 10240          // avg 8184 edges/bucket; +22 sigma headroom
#define TILE 8192           // edges per partition tile

__device__ __forceinline__ u16 f2bf(float f) {
  union { float f; unsigned u; } v; v.f = f;
  unsigned r = v.u + 0x7FFFu + ((v.u >> 16) & 1u);  // RNE
  return (u16)(r >> 16);
}
__device__ __forceinline__ float bf2f(u16 h) {
  union { unsigned u; float f; } v; v.u = ((unsigned)h) << 16;
  return v.f;
}

// transpose + bf16-convert weights: w1t[n][k] (64x256), w2t[n][k] (64x64)
__global__ void k_wprep(const float* __restrict__ W1, const float* __restrict__ W2,
                        u16* __restrict__ w1t, u16* __restrict__ w2t) {
  int t = blockIdx.x * blockDim.x + threadIdx.x;
  if (t < 64 * 256) {
    int n = t >> 8, k = t & 255;
    w1t[t] = f2bf(W1[k * 64 + n]);
  }
  int t2 = t - 64 * 256;
  if (t2 >= 0 && t2 < 64 * 64) {
    int n = t2 >> 6, k = t2 & 63;
    w2t[t2] = f2bf(W2[k * 64 + n]);
  }
}

// ---------------- phase A: LDS-staged bucket partition ----------------
// Edge packed as u32: src (bits 0-19) | dloc (bits 20-27). Int LDS atomics only.

__global__ __launch_bounds__(1024) void k_part(const int* __restrict__ e_src,
                                               const int* __restrict__ e_dst,
                                               int* __restrict__ bcnt,
                                               u32* __restrict__ bedge, int E) {
  __shared__ int lcnt[512];
  __shared__ int lscan[512];
  __shared__ int gbase[512];
  __shared__ int wsum[8];
  __shared__ u32 stag[TILE];
  __shared__ int dest[TILE];
  int t = threadIdx.x;
  int base = blockIdx.x * TILE;
  int here = E - base; if (here > TILE) here = TILE;

  if (t < 512) lcnt[t] = 0;
  __syncthreads();

  u32 m[8]; int bk[8]; int rk[8];
#pragma unroll
  for (int k = 0; k < 8; ++k) {
    int e = base + t + k * 1024;
    if (e < E) {
      int s = e_src[e], d = e_dst[e];
      bk[k] = d >> BSHIFT;
      m[k] = (u32)s | ((u32)(d & (BNODES - 1)) << 20);
      rk[k] = atomicAdd(&lcnt[bk[k]], 1);
    } else bk[k] = -1;
  }
  __syncthreads();

  // exclusive scan of lcnt[0..511] by threads 0..511 (8 waves)
  int lane = t & 63, w = t >> 6;
  int v = 0, x = 0;
  if (t < 512) { v = lcnt[t]; x = v; }
#pragma unroll
  for (int off = 1; off < 64; off <<= 1) {
    int y = __shfl_up(x, off);
    if (lane >= off) x += y;
  }
  if (t < 512 && lane == 63) wsum[w] = x;
  __syncthreads();
  if (t < 512) {
    int wo = 0;
    for (int i = 0; i < w; ++i) wo += wsum[i];
    lscan[t] = x - v + wo;
  }
  __syncthreads();

  // reserve global space per bucket
  if (t < NBUK) gbase[t] = t * BCAP + atomicAdd(&bcnt[t], lcnt[t]);
  __syncthreads();

  // place into LDS staging ordered by bucket
#pragma unroll
  for (int k = 0; k < 8; ++k) {
    if (bk[k] >= 0) {
      int p = lscan[bk[k]] + rk[k];
      stag[p] = m[k];
      dest[p] = gbase[bk[k]] + rk[k];
    }
  }
  __syncthreads();

  // coalesced copy-out (runs of same-bucket edges are contiguous)
#pragma unroll
  for (int k = 0; k < 8; ++k) {
    int p = t + k * 1024;
    if (p < here) bedge[dest[p]] = stag[p];
  }
}

// ---------------- phase B: per-bucket counting sort by dst (in-place) ----------------
// Emits rptr/rcnt/dinv. Int LDS atomics only.

__global__ __launch_bounds__(1024) void k_sort(const int* __restrict__ bcnt,
                                               u32* __restrict__ bedge,
                                               int* __restrict__ rptr,
                                               int* __restrict__ rcnt,
                                               float* __restrict__ dinv, int N) {
  __shared__ u32 stag[BCAP];     // 40 KB
  __shared__ int hist[BNODES];
  __shared__ int cur[BNODES];
  __shared__ int wsum4[4];
  int b = blockIdx.x, t = threadIdx.x;
  if (t < BNODES) hist[t] = 0;
  __syncthreads();
  int n = bcnt[b]; if (n > BCAP) n = BCAP;
  u32* be = bedge + (size_t)b * BCAP;

  for (int i = t; i < n; i += 1024) atomicAdd(&hist[be[i] >> 20], 1);
  __syncthreads();

  // exclusive scan of hist[0..255] by threads 0..255 (4 waves)
  int lane = t & 63, w = t >> 6;
  int v = 0, x = 0;
  if (t < BNODES) { v = hist[t]; x = v; }
#pragma unroll
  for (int off = 1; off < 64; off <<= 1) {
    int y = __shfl_up(x, off);
    if (lane >= off) x += y;
  }
  if (t < BNODES && lane == 63) wsum4[w] = x;
  __syncthreads();
  if (t < BNODES) {
    int wo = 0;
    for (int i = 0; i < w; ++i) wo += wsum4[i];
    int ex = x - v + wo;
    cur[t] = ex;
    int node = (b << BSHIFT) + t;
    if (node < N) {
      rptr[node] = b * BCAP + ex;
      rcnt[node] = v;
      dinv[node] = rsqrtf((float)(v + 1));  // +1 self-loop
    }
  }
  __syncthreads();

  // rank + scatter into LDS (sorted by dloc)
  for (int i = t; i < n; i += 1024) {
    u32 m = be[i];
    int p = atomicAdd(&cur[m >> 20], 1);
    stag[p] = m;
  }
  __syncthreads();

  // in-place coalesced writeback
  for (int i = t; i < n; i += 1024) be[i] = stag[i];
}

// ---------------- gemm1 (MFMA 16x16x32 bf16), wave = 16 rows x ALL 64 cols ----------------
// A[m=lane&15][k=quad*8+j], B[n=lane&15][k=quad*8+j], D: col=lane&15, row=quad*4+reg.
// h'[row] = dinv[row] * (x@W1)[row].
// launch_bounds(256,1): waves-per-eu=1 frees the register allocator so the
// 16 hoisted A-loads stay clustered (round 6: default occupancy target squeezed
// VGPR to 32 and serialized the loads -> 79us latency-bound).

__global__ __launch_bounds__(256, 1) void k_gemm1(const float* __restrict__ x,
                                                  const u16* __restrict__ w1t,
                                                  const float* __restrict__ dinv,
                                                  u16* __restrict__ h1, int N) {
  int lane = threadIdx.x & 63;
  int wave = threadIdx.x >> 6;
  int rowbase = (blockIdx.x * 4 + wave) * 16;
  if (rowbase >= N) return;  // N % 16 == 0: tiles never straddle
  int mn = lane & 15, quad = lane >> 4;
  const float* arow = x + (size_t)(rowbase + mn) * IN_CH + quad * 8;

  // hoist all 16 A loads (64 VGPR) -> one vmcnt wait
  float4 a[16];
#pragma unroll
  for (int kc = 0; kc < 8; ++kc) {
    a[2 * kc] = *(const float4*)(arow + kc * 32);
    a[2 * kc + 1] = *(const float4*)(arow + kc * 32 + 4);
  }
  // convert once to bf16 frags (32 VGPR)
  u16x8 au[8];
#pragma unroll
  for (int kc = 0; kc < 8; ++kc) {
    float4 a0 = a[2 * kc], a1 = a[2 * kc + 1];
    au[kc][0] = f2bf(a0.x); au[kc][1] = f2bf(a0.y);
    au[kc][2] = f2bf(a0.z); au[kc][3] = f2bf(a0.w);
    au[kc][4] = f2bf(a1.x); au[kc][5] = f2bf(a1.y);
    au[kc][6] = f2bf(a1.z); au[kc][7] = f2bf(a1.w);
  }

  f32x4 acc[4] = {{0.f, 0.f, 0.f, 0.f}, {0.f, 0.f, 0.f, 0.f},
                  {0.f, 0.f, 0.f, 0.f}, {0.f, 0.f, 0.f, 0.f}};
#pragma unroll
  for (int c = 0; c < 4; ++c) {
    const u16* brow = w1t + (c * 16 + mn) * IN_CH + quad * 8;
    u16x8 bu[8];  // clustered, L1-hot (B is 32 KB shared chip-wide)
#pragma unroll
    for (int kc = 0; kc < 8; ++kc) bu[kc] = *(const u16x8*)(brow + kc * 32);
#pragma unroll
    for (int kc = 0; kc < 8; ++kc)
      acc[c] = __builtin_amdgcn_mfma_f32_16x16x32_bf16(
          __builtin_bit_cast(bf16x8, au[kc]), __builtin_bit_cast(bf16x8, bu[kc]),
          acc[c], 0, 0, 0);
  }
#pragma unroll
  for (int r = 0; r < 4; ++r) {
    int row = rowbase + quad * 4 + r;
    float dv = dinv[row];
#pragma unroll
    for (int c = 0; c < 4; ++c)
      h1[(size_t)row * HID + c * 16 + mn] = f2bf(dv * acc[c][r]);
  }
}

__global__ __launch_bounds__(256) void k_gemm2(const u16* __restrict__ g1,
                                               const u16* __restrict__ w2t,
                                               const float* __restrict__ dinv,
                                               u16* __restrict__ h2) {
  int lane = threadIdx.x & 63;
  int wave = threadIdx.x >> 6;
  int rowbase = blockIdx.x * 16;
  int colbase = wave * 16;
  int mn = lane & 15, quad = lane >> 4;
  const u16* arow = g1 + (size_t)(rowbase + mn) * HID + quad * 8;
  const u16* brow = w2t + (colbase + mn) * HID + quad * 8;
  u16x8 au0 = *(const u16x8*)(arow);
  u16x8 au1 = *(const u16x8*)(arow + 32);
  u16x8 bu0 = *(const u16x8*)(brow);
  u16x8 bu1 = *(const u16x8*)(brow + 32);
  f32x4 acc = {0.f, 0.f, 0.f, 0.f};
  acc = __builtin_amdgcn_mfma_f32_16x16x32_bf16(
      __builtin_bit_cast(bf16x8, au0), __builtin_bit_cast(bf16x8, bu0), acc, 0, 0, 0);
  acc = __builtin_amdgcn_mfma_f32_16x16x32_bf16(
      __builtin_bit_cast(bf16x8, au1), __builtin_bit_cast(bf16x8, bu1), acc, 0, 0, 0);
#pragma unroll
  for (int r = 0; r < 4; ++r) {
    int row = rowbase + quad * 4 + r;
    h2[(size_t)row * HID + colbase + mn] = f2bf(dinv[row] * acc[r]);
  }
}

// ---------------- aggregation: wave per node, scalar edges, multi-accumulator ----------------
// out[i] = dinv_i * (sum_e h'[src_e] + h'[i]) + bias
// launch_bounds(256,4): <=128 VGPR so the 16-gather batch keeps its registers.

template <bool RELU, bool BF16OUT>
__global__ __launch_bounds__(256, 4) void k_agg(const u16* __restrict__ hin,
                                                const int* __restrict__ rptr,
                                                const int* __restrict__ rcnt,
                                                const u32* __restrict__ sedge,
                                                const float* __restrict__ bias,
                                                void* __restrict__ outv, int N) {
  int wid = blockIdx.x * 4 + (threadIdx.x >> 6);
  int lane = threadIdx.x & 63;
  if (wid >= N) return;
  int start = __builtin_amdgcn_readfirstlane(rptr[wid]);
  int len = __builtin_amdgcn_readfirstlane(rcnt[wid]);
  float di = rsqrtf((float)(len + 1));
  float a0 = bf2f(hin[(size_t)wid * HID + lane]);  // self-loop: dinv*h'[i]
  float a1 = 0.f, a2 = 0.f, a3 = 0.f;
  const u32* se = sedge + start;
  int j = 0;
  for (; j + 16 <= len; j += 16) {
    u16 v[16];
#pragma unroll
    for (int k = 0; k < 16; ++k) {
      int e = (int)(se[j + k] & 0xFFFFF);  // wave-uniform -> s_load batch
      v[k] = hin[(size_t)e * HID + lane];  // 16 gathers in flight
    }
#pragma unroll
    for (int k = 0; k < 16; ++k) {
      float f = bf2f(v[k]);
      if ((k & 3) == 0) a0 += f;
      else if ((k & 3) == 1) a1 += f;
      else if ((k & 3) == 2) a2 += f;
      else a3 += f;
    }
  }
  if (j + 8 <= len) {
    u16 v[8];
#pragma unroll
    for (int k = 0; k < 8; ++k) {
      int e = (int)(se[j + k] & 0xFFFFF);
      v[k] = hin[(size_t)e * HID + lane];
    }
#pragma unroll
    for (int k = 0; k < 8; ++k) {
      float f = bf2f(v[k]);
      if ((k & 3) == 0) a0 += f;
      else if ((k & 3) == 1) a1 += f;
      else if ((k & 3) == 2) a2 += f;
      else a3 += f;
    }
    j += 8;
  }
  if (j + 4 <= len) {
    u16 v[4];
#pragma unroll
    for (int k = 0; k < 4; ++k) {
      int e = (int)(se[j + k] & 0xFFFFF);
      v[k] = hin[(size_t)e * HID + lane];
    }
    a0 += bf2f(v[0]); a1 += bf2f(v[1]); a2 += bf2f(v[2]); a3 += bf2f(v[3]);
    j += 4;
  }
  for (; j < len; ++j) {
    int e = (int)(se[j] & 0xFFFFF);
    a0 += bf2f(hin[(size_t)e * HID + lane]);
  }
  float acc = (a0 + a1) + (a2 + a3);
  acc = di * acc + bias[lane];
  if (RELU) acc = fmaxf(acc, 0.f);
  if (BF16OUT) ((u16*)outv)[(size_t)wid * HID + lane] = f2bf(acc);
  else ((float*)outv)[(size_t)wid * HID + lane] = acc;
}

// ---------------- host ----------------

extern "C" void kernel_launch(void* const* d_in, const int* in_sizes, int n_in,
                              void* d_out, int out_size, void* d_ws, size_t ws_size,
                              hipStream_t stream) {
  const float* x = (const float*)d_in[0];
  const int* ei = (const int*)d_in[1];  // [2][E] int32
  const float* W1 = (const float*)d_in[2];
  const float* b1 = (const float*)d_in[3];
  const float* W2 = (const float*)d_in[4];
  const float* b2 = (const float*)d_in[5];
  float* out = (float*)d_out;

  const int N = in_sizes[0] / IN_CH;  // 100000
  const int E = in_sizes[1] / 2;      // 3200000
  const int* e_src = ei;
  const int* e_dst = ei + E;

  size_t off = 0;
  auto carve = [&](size_t bytes) -> char* {
    char* p = (char*)d_ws + off;
    off += (bytes + 255) & ~(size_t)255;
    return p;
  };
  int* bcnt = (int*)carve((size_t)NBUK * 4);
  u32* bedge = (u32*)carve((size_t)NBUK * BCAP * 4);  // 16 MB
  int* rptr = (int*)carve((size_t)N * 4);
  int* rcnt = (int*)carve((size_t)N * 4);
  float* dinv = (float*)carve((size_t)N * 4);
  u16* w1t = (u16*)carve(64 * 256 * 2);
  u16* w2t = (u16*)carve(64 * 64 * 2);
  u16* h1 = (u16*)carve((size_t)N * HID * 2);  // reused for h2
  u16* g1 = (u16*)carve((size_t)N * HID * 2);

  const int n_tiles = (E + TILE - 1) / TILE;  // 391
  const int nb_g1 = (N + 63) / 64;            // 64 rows per block (4 waves x 16)

  hipMemsetAsync(bcnt, 0, (size_t)NBUK * 4, stream);
  k_wprep<<<(64 * 256 + 64 * 64 + 255) / 256, 256, 0, stream>>>(W1, W2, w1t, w2t);
  k_part<<<n_tiles, 1024, 0, stream>>>(e_src, e_dst, bcnt, bedge, E);
  k_sort<<<NBUK, 1024, 0, stream>>>(bcnt, bedge, rptr, rcnt, dinv, N);
  k_gemm1<<<nb_g1, 256, 0, stream>>>(x, w1t, dinv, h1, N);
  k_agg<true, true><<<(N + 3) / 4, 256, 0, stream>>>(h1, rptr, rcnt, bedge, b1, g1, N);
  k_gemm2<<<N / 16, 256, 0, stream>>>(g1, w2t, dinv, h1);
  k_agg<false, false><<<(N + 3) / 4, 256, 0, stream>>>(h1, rptr, rcnt, bedge, b2, out, N);
}